// Round 2
// 634.371 us; speedup vs baseline: 1.1263x; 1.1263x over previous
//
#include <hip/hip_runtime.h>

#define EPS 1e-4f

constexpr int Bn = 64;
constexpr int Nn = 1024;
constexpr int Mn = 1024;
constexpr int NSPLIT = 16;           // fuse0/rowcol row chunks -> 64 rows/block
constexpr int CHUNK  = Nn / NSPLIT;  // 64
constexpr int SLOT   = 16;           // partial col-sum slots per sample (1/block)

typedef float f32x4 __attribute__((ext_vector_type(4)));

// ---- fp16 helpers via clang builtin _Float16 (no header dependency).
// Values in [1e-4, ~1.0] -> fp16 normal range; (​_Float16) cast is RNE.
// fp16 gives 8x the mantissa of bf16 at identical memory traffic.
__device__ __forceinline__ unsigned pkh2(float a, float b) {
    union { _Float16 h; unsigned short u; } ta, tb;
    ta.h = (_Float16)a; tb.h = (_Float16)b;
    return (unsigned)ta.u | ((unsigned)tb.u << 16);
}
__device__ __forceinline__ float lo16(unsigned v) {
    union { unsigned short u; _Float16 h; } t; t.u = (unsigned short)(v & 0xffffu);
    return (float)t.h;
}
__device__ __forceinline__ float hi16(unsigned v) {
    union { unsigned short u; _Float16 h; } t; t.u = (unsigned short)(v >> 16);
    return (float)t.h;
}

// ---- pass 0 fused: compress s+eps -> fp16 sc AND accumulate unmasked col sums.
// Block 256: threads 0..127 take row n (cols 8t..8t+7), threads 128..255 row n+1.
// Halves combined through LDS -> ONE partial slot per block (16/sample).
// s loads are non-temporal: keep the freshly written sc resident in L3.
__global__ __launch_bounds__(256) void fuse0_kernel(
        const float* __restrict__ s, unsigned short* __restrict__ sc,
        float* __restrict__ p) {
    __shared__ float4 red[256];      // 4 KB: half-1 partials
    const int b = blockIdx.x, sp = blockIdx.y;
    const int t = threadIdx.x, half = t >> 7, tc = t & 127;
    float acc[8];
    #pragma unroll
    for (int k = 0; k < 8; ++k) acc[k] = 0.f;
    for (int j = 0; j < CHUNK; j += 2) {
        const int n = sp * CHUNK + j + half;
        const size_t roff = ((size_t)b * Nn + n) * Mn;
        const f32x4* src = reinterpret_cast<const f32x4*>(s + roff) + 2 * tc;
        f32x4 v0 = __builtin_nontemporal_load(src);
        f32x4 v1 = __builtin_nontemporal_load(src + 1);
        v0 += EPS; v1 += EPS;
        acc[0] += v0.x; acc[1] += v0.y; acc[2] += v0.z; acc[3] += v0.w;
        acc[4] += v1.x; acc[5] += v1.y; acc[6] += v1.z; acc[7] += v1.w;
        uint4 wpk = { pkh2(v0.x, v0.y), pkh2(v0.z, v0.w),
                      pkh2(v1.x, v1.y), pkh2(v1.z, v1.w) };
        reinterpret_cast<uint4*>(sc + roff)[tc] = wpk;
    }
    if (half) {
        red[tc * 2]     = make_float4(acc[0], acc[1], acc[2], acc[3]);
        red[tc * 2 + 1] = make_float4(acc[4], acc[5], acc[6], acc[7]);
    }
    __syncthreads();
    if (!half) {
        const float4 r0 = red[tc * 2], r1 = red[tc * 2 + 1];
        float* pp = p + ((size_t)(b * SLOT + sp)) * Mn + tc * 8;
        float4 o0 = {acc[0] + r0.x, acc[1] + r0.y, acc[2] + r0.z, acc[3] + r0.w};
        float4 o1 = {acc[4] + r1.x, acc[5] + r1.y, acc[6] + r1.z, acc[7] + r1.w};
        *reinterpret_cast<float4*>(pp)     = o0;
        *reinterpret_cast<float4*>(pp + 4) = o1;
    }
}

// ---- reduce 16 partial slots -> masked, guarded reciprocal c[b][m].
// grid (B, 4), 256 threads, one column/thread: compile-time 16-deep unroll
// gives 16 loads in flight (was: 64 blocks, runtime-count serial loop).
__global__ __launch_bounds__(256) void col_final_kernel(
        const float* __restrict__ p, const int* __restrict__ ncols,
        float* __restrict__ c) {
    const int b = blockIdx.x;
    const int m = blockIdx.y * 256 + threadIdx.x;
    float sum = 0.f;
    #pragma unroll
    for (int k = 0; k < SLOT; ++k)
        sum += p[((size_t)(b * SLOT + k)) * Mn + m];
    c[(size_t)b * Mn + m] = (m < ncols[b] && sum > 0.f) ? 1.f / sum : 0.f;
}

// ---- FUSED row-pass + col-pass over fp16 sc, one sweep.
// One wave per 16 rows, processed 2 AT A TIME: two independent 6-deep
// butterfly chains per step (ILP 2) instead of one serial chain per row.
// The 4 waves' col partials combine through LDS -> ONE slot per block.
__global__ __launch_bounds__(256) void rowcol_kernel(
        const unsigned short* __restrict__ sc, const float* __restrict__ c,
        const int* __restrict__ nrows, float* __restrict__ p) {
    __shared__ float4 red[4][256];   // 16 KB
    const int b = blockIdx.x;
    const int t = threadIdx.x, w = t >> 6, l = t & 63;
    const int n0 = blockIdx.y * 64 + w * 16;
    const float4* cb = reinterpret_cast<const float4*>(c + (size_t)b * Mn);
    const float4 c0 = cb[2 * l], c1 = cb[2 * l + 1];
    const float4 c2 = cb[128 + 2 * l], c3 = cb[128 + 2 * l + 1];
    const int nr = nrows[b];
    float acc[16];
    #pragma unroll
    for (int k = 0; k < 16; ++k) acc[k] = 0.f;
    const uint4* base = reinterpret_cast<const uint4*>(sc + ((size_t)b * Nn + n0) * Mn);
    for (int j = 0; j < 16; j += 2) {
        const uint4* r0 = base + (size_t)j * 128;   // 128 uint4 per row
        const uint4 a0 = r0[l],       d0 = r0[64 + l];
        const uint4 a1 = r0[128 + l], d1 = r0[192 + l];
        const float x0 = lo16(a0.x),  x1 = hi16(a0.x),  x2 = lo16(a0.y),  x3 = hi16(a0.y);
        const float x4 = lo16(a0.z),  x5 = hi16(a0.z),  x6 = lo16(a0.w),  x7 = hi16(a0.w);
        const float x8 = lo16(d0.x),  x9 = hi16(d0.x),  x10 = lo16(d0.y), x11 = hi16(d0.y);
        const float x12 = lo16(d0.z), x13 = hi16(d0.z), x14 = lo16(d0.w), x15 = hi16(d0.w);
        const float y0 = lo16(a1.x),  y1 = hi16(a1.x),  y2 = lo16(a1.y),  y3 = hi16(a1.y);
        const float y4 = lo16(a1.z),  y5 = hi16(a1.z),  y6 = lo16(a1.w),  y7 = hi16(a1.w);
        const float y8 = lo16(d1.x),  y9 = hi16(d1.x),  y10 = lo16(d1.y), y11 = hi16(d1.y);
        const float y12 = lo16(d1.z), y13 = hi16(d1.z), y14 = lo16(d1.w), y15 = hi16(d1.w);
        float part0 = x0 * c0.x + x1 * c0.y + x2 * c0.z + x3 * c0.w
                    + x4 * c1.x + x5 * c1.y + x6 * c1.z + x7 * c1.w
                    + x8 * c2.x + x9 * c2.y + x10 * c2.z + x11 * c2.w
                    + x12 * c3.x + x13 * c3.y + x14 * c3.z + x15 * c3.w;
        float part1 = y0 * c0.x + y1 * c0.y + y2 * c0.z + y3 * c0.w
                    + y4 * c1.x + y5 * c1.y + y6 * c1.z + y7 * c1.w
                    + y8 * c2.x + y9 * c2.y + y10 * c2.z + y11 * c2.w
                    + y12 * c3.x + y13 * c3.y + y14 * c3.z + y15 * c3.w;
        #pragma unroll
        for (int off = 1; off < 64; off <<= 1) {
            part0 += __shfl_xor(part0, off, 64);
            part1 += __shfl_xor(part1, off, 64);
        }
        const int n = n0 + j;
        const float rv0 = (n < nr && part0 > 0.f) ? 1.f / part0 : 0.f;
        const float rv1 = (n + 1 < nr && part1 > 0.f) ? 1.f / part1 : 0.f;
        acc[0]  += x0 * rv0 + y0 * rv1;   acc[1]  += x1 * rv0 + y1 * rv1;
        acc[2]  += x2 * rv0 + y2 * rv1;   acc[3]  += x3 * rv0 + y3 * rv1;
        acc[4]  += x4 * rv0 + y4 * rv1;   acc[5]  += x5 * rv0 + y5 * rv1;
        acc[6]  += x6 * rv0 + y6 * rv1;   acc[7]  += x7 * rv0 + y7 * rv1;
        acc[8]  += x8 * rv0 + y8 * rv1;   acc[9]  += x9 * rv0 + y9 * rv1;
        acc[10] += x10 * rv0 + y10 * rv1; acc[11] += x11 * rv0 + y11 * rv1;
        acc[12] += x12 * rv0 + y12 * rv1; acc[13] += x13 * rv0 + y13 * rv1;
        acc[14] += x14 * rv0 + y14 * rv1; acc[15] += x15 * rv0 + y15 * rv1;
    }
    // wave-partial f4 index q maps to column-f4 index q (identity): combine in LDS
    red[w][2 * l]       = make_float4(acc[0], acc[1], acc[2], acc[3]);
    red[w][2 * l + 1]   = make_float4(acc[4], acc[5], acc[6], acc[7]);
    red[w][128 + 2 * l] = make_float4(acc[8], acc[9], acc[10], acc[11]);
    red[w][129 + 2 * l] = make_float4(acc[12], acc[13], acc[14], acc[15]);
    __syncthreads();
    const float4 r0 = red[0][t], r1 = red[1][t], r2 = red[2][t], r3 = red[3][t];
    float4 o = { r0.x + r1.x + r2.x + r3.x, r0.y + r1.y + r2.y + r3.y,
                 r0.z + r1.z + r2.z + r3.z, r0.w + r1.w + r2.w + r3.w };
    float* pp = p + ((size_t)(b * SLOT) + blockIdx.y) * Mn;
    reinterpret_cast<float4*>(pp)[t] = o;
}

// ---- final pass: f32 s, compute last row factor in-wave and write output.
// Non-temporal loads/stores: pure streaming, keep L3 clean.
__global__ __launch_bounds__(256) void final_kernel(
        const float* __restrict__ s, const float* __restrict__ c,
        const int* __restrict__ nrows, float* __restrict__ out) {
    const int b = blockIdx.x;
    const int t = threadIdx.x, w = t >> 6, l = t & 63;
    const int n0 = blockIdx.y * 32 + w * 8;
    const float4* cb = reinterpret_cast<const float4*>(c + (size_t)b * Mn);
    float4 cc[4];
    #pragma unroll
    for (int k = 0; k < 4; ++k) cc[k] = cb[64 * k + l];
    const int nr = nrows[b];
    for (int j = 0; j < 8; ++j) {
        const int n = n0 + j;
        const size_t roff = ((size_t)b * Nn + n) * Mn;
        const f32x4* row = reinterpret_cast<const f32x4*>(s + roff);
        f32x4 a[4];
        float part = 0.f;
        #pragma unroll
        for (int k = 0; k < 4; ++k) {
            a[k] = __builtin_nontemporal_load(row + 64 * k + l);
            a[k] += EPS;
            part += a[k].x * cc[k].x + a[k].y * cc[k].y
                  + a[k].z * cc[k].z + a[k].w * cc[k].w;
        }
        #pragma unroll
        for (int off = 1; off < 64; off <<= 1) part += __shfl_xor(part, off, 64);
        const float rv = (n < nr && part > 0.f) ? 1.f / part : 0.f;
        f32x4* orow = reinterpret_cast<f32x4*>(out + roff);
        #pragma unroll
        for (int k = 0; k < 4; ++k) {
            f32x4 o;
            o.x = a[k].x * cc[k].x * rv;
            o.y = a[k].y * cc[k].y * rv;
            o.z = a[k].z * cc[k].z * rv;
            o.w = a[k].w * cc[k].w * rv;
            __builtin_nontemporal_store(o, orow + 64 * k + l);
        }
    }
}

extern "C" void kernel_launch(void* const* d_in, const int* in_sizes, int n_in,
                              void* d_out, int out_size, void* d_ws, size_t ws_size,
                              hipStream_t stream) {
    const float* s     = (const float*)d_in[0];
    const int*   nrows = (const int*)d_in[1];
    const int*   ncols = (const int*)d_in[2];
    float* out = (float*)d_out;

    // workspace: sc fp16 [B*N*M] (128 MiB) | p [B*16*M] (4 MB) | c (256 KB)
    unsigned short* sc = (unsigned short*)d_ws;
    float* p = (float*)(sc + (size_t)Bn * Nn * Mn);
    float* c = p + (size_t)Bn * SLOT * Mn;

    // i=0: col pass fused with fp16 compression (unmasked, r==1)
    fuse0_kernel<<<dim3(Bn, NSPLIT), 256, 0, stream>>>(s, sc, p);
    col_final_kernel<<<dim3(Bn, Mn / 256), 256, 0, stream>>>(p, ncols, c);
    // i=1..8: four fused (row-norm + col-norm) sweeps over compressed sc
    for (int it = 0; it < 4; ++it) {
        rowcol_kernel<<<dim3(Bn, Nn / 64), 256, 0, stream>>>(sc, c, nrows, p);
        col_final_kernel<<<dim3(Bn, Mn / 256), 256, 0, stream>>>(p, ncols, c);
    }
    // i=9: final row normalization fused with output write (f32 precision)
    final_kernel<<<dim3(Bn, Nn / 32), 256, 0, stream>>>(s, c, nrows, out);
}

// Round 3
// 623.621 us; speedup vs baseline: 1.1457x; 1.0172x over previous
//
#include <hip/hip_runtime.h>

#define EPS 1e-4f

constexpr int Bn = 64;
constexpr int Nn = 1024;
constexpr int Mn = 1024;
constexpr int NSPLIT = 16;           // fuse0/rowcol row chunks -> 64 rows/block
constexpr int CHUNK  = Nn / NSPLIT;  // 64
constexpr int SLOT   = 16;           // partial col-sum slots per sample (1/block)

typedef float f32x4 __attribute__((ext_vector_type(4)));

// ---- fp16 helpers via clang builtin _Float16 (no header dependency).
__device__ __forceinline__ unsigned pkh2(float a, float b) {
    union { _Float16 h; unsigned short u; } ta, tb;
    ta.h = (_Float16)a; tb.h = (_Float16)b;
    return (unsigned)ta.u | ((unsigned)tb.u << 16);
}
__device__ __forceinline__ float lo16(unsigned v) {
    union { unsigned short u; _Float16 h; } t; t.u = (unsigned short)(v & 0xffffu);
    return (float)t.h;
}
__device__ __forceinline__ float hi16(unsigned v) {
    union { unsigned short u; _Float16 h; } t; t.u = (unsigned short)(v >> 16);
    return (float)t.h;
}

// ---- shared: reduce SLOT partial col-sum slots from pin -> masked reciprocal
// c[1024] in LDS. Thread t owns cols 4t..4t+3. Identical f32 sum order as the
// old col_final kernel -> bitwise-identical numerics.
__device__ __forceinline__ void fold_c(const float* __restrict__ pin,
                                       const int* __restrict__ ncols,
                                       int b, int t, float* cs) {
    const int m0 = t * 4;
    f32x4 s4 = {0.f, 0.f, 0.f, 0.f};
    #pragma unroll
    for (int k = 0; k < SLOT; ++k)
        s4 += *reinterpret_cast<const f32x4*>(pin + ((size_t)(b * SLOT + k)) * Mn + m0);
    const int nc = ncols[b];
    f32x4 r;
    r.x = (m0 + 0 < nc && s4.x > 0.f) ? 1.f / s4.x : 0.f;
    r.y = (m0 + 1 < nc && s4.y > 0.f) ? 1.f / s4.y : 0.f;
    r.z = (m0 + 2 < nc && s4.z > 0.f) ? 1.f / s4.z : 0.f;
    r.w = (m0 + 3 < nc && s4.w > 0.f) ? 1.f / s4.w : 0.f;
    *reinterpret_cast<f32x4*>(&cs[m0]) = r;
}

// ---- pass 0 fused: compress s+eps -> fp16 sc AND accumulate unmasked col sums.
// Depth-1 register prefetch: next row-pair's loads issued before current compute.
__global__ __launch_bounds__(256) void fuse0_kernel(
        const float* __restrict__ s, unsigned short* __restrict__ sc,
        float* __restrict__ p) {
    __shared__ float4 red[256];      // 4 KB: half-1 partials
    const int b = blockIdx.x, sp = blockIdx.y;
    const int t = threadIdx.x, half = t >> 7, tc = t & 127;
    float acc[8];
    #pragma unroll
    for (int k = 0; k < 8; ++k) acc[k] = 0.f;
    const size_t roff0 = ((size_t)b * Nn + sp * CHUNK + half) * Mn;
    const f32x4* src0 = reinterpret_cast<const f32x4*>(s + roff0) + 2 * tc;
    f32x4 v0 = __builtin_nontemporal_load(src0);
    f32x4 v1 = __builtin_nontemporal_load(src0 + 1);
    for (int j = 0; j < CHUNK; j += 2) {
        f32x4 n0 = {}, n1 = {};
        if (j < CHUNK - 2) {
            const f32x4* nsrc = src0 + (size_t)(j + 2) * (Mn / 4);
            n0 = __builtin_nontemporal_load(nsrc);
            n1 = __builtin_nontemporal_load(nsrc + 1);
        }
        f32x4 w0 = v0 + EPS, w1 = v1 + EPS;
        acc[0] += w0.x; acc[1] += w0.y; acc[2] += w0.z; acc[3] += w0.w;
        acc[4] += w1.x; acc[5] += w1.y; acc[6] += w1.z; acc[7] += w1.w;
        uint4 wpk = { pkh2(w0.x, w0.y), pkh2(w0.z, w0.w),
                      pkh2(w1.x, w1.y), pkh2(w1.z, w1.w) };
        const size_t roff = roff0 + (size_t)j * Mn;
        reinterpret_cast<uint4*>(sc + roff)[tc] = wpk;
        v0 = n0; v1 = n1;
    }
    if (half) {
        red[tc * 2]     = make_float4(acc[0], acc[1], acc[2], acc[3]);
        red[tc * 2 + 1] = make_float4(acc[4], acc[5], acc[6], acc[7]);
    }
    __syncthreads();
    if (!half) {
        const float4 r0 = red[tc * 2], r1 = red[tc * 2 + 1];
        float* pp = p + ((size_t)(b * SLOT + sp)) * Mn + tc * 8;
        float4 o0 = {acc[0] + r0.x, acc[1] + r0.y, acc[2] + r0.z, acc[3] + r0.w};
        float4 o1 = {acc[4] + r1.x, acc[5] + r1.y, acc[6] + r1.z, acc[7] + r1.w};
        *reinterpret_cast<float4*>(pp)     = o0;
        *reinterpret_cast<float4*>(pp + 4) = o1;
    }
}

// ---- FUSED (col-finalize + row-pass + col-pass) over fp16 sc, one sweep.
// Block start: reduce pin slots -> c in LDS (no separate col_final dispatch).
// Main loop: 2 rows/step, depth-1 register prefetch of the next row pair.
// Reads pin, writes pout (ping-pong: no intra-dispatch RW hazard).
__global__ __launch_bounds__(256) void rowcol_kernel(
        const unsigned short* __restrict__ sc, const float* __restrict__ pin,
        const int* __restrict__ nrows, const int* __restrict__ ncols,
        float* __restrict__ pout) {
    __shared__ float cs[1024];       // 4 KB: column reciprocals
    __shared__ float4 red[4][256];   // 16 KB
    const int b = blockIdx.x;
    const int t = threadIdx.x, w = t >> 6, l = t & 63;
    fold_c(pin, ncols, b, t, cs);
    __syncthreads();
    const f32x4 c0 = *reinterpret_cast<const f32x4*>(&cs[8 * l]);
    const f32x4 c1 = *reinterpret_cast<const f32x4*>(&cs[8 * l + 4]);
    const f32x4 c2 = *reinterpret_cast<const f32x4*>(&cs[512 + 8 * l]);
    const f32x4 c3 = *reinterpret_cast<const f32x4*>(&cs[512 + 8 * l + 4]);
    const int n0 = blockIdx.y * 64 + w * 16;
    const int nr = nrows[b];
    float acc[16];
    #pragma unroll
    for (int k = 0; k < 16; ++k) acc[k] = 0.f;
    const uint4* base = reinterpret_cast<const uint4*>(sc + ((size_t)b * Nn + n0) * Mn);
    uint4 a0 = base[l], d0 = base[64 + l], a1 = base[128 + l], d1 = base[192 + l];
    for (int j = 0; j < 16; j += 2) {
        uint4 na0 = {}, nd0 = {}, na1 = {}, nd1 = {};
        if (j < 14) {
            const uint4* nx = base + (size_t)(j + 2) * 128;
            na0 = nx[l]; nd0 = nx[64 + l]; na1 = nx[128 + l]; nd1 = nx[192 + l];
        }
        const float x0 = lo16(a0.x),  x1 = hi16(a0.x),  x2 = lo16(a0.y),  x3 = hi16(a0.y);
        const float x4 = lo16(a0.z),  x5 = hi16(a0.z),  x6 = lo16(a0.w),  x7 = hi16(a0.w);
        const float x8 = lo16(d0.x),  x9 = hi16(d0.x),  x10 = lo16(d0.y), x11 = hi16(d0.y);
        const float x12 = lo16(d0.z), x13 = hi16(d0.z), x14 = lo16(d0.w), x15 = hi16(d0.w);
        const float y0 = lo16(a1.x),  y1 = hi16(a1.x),  y2 = lo16(a1.y),  y3 = hi16(a1.y);
        const float y4 = lo16(a1.z),  y5 = hi16(a1.z),  y6 = lo16(a1.w),  y7 = hi16(a1.w);
        const float y8 = lo16(d1.x),  y9 = hi16(d1.x),  y10 = lo16(d1.y), y11 = hi16(d1.y);
        const float y12 = lo16(d1.z), y13 = hi16(d1.z), y14 = lo16(d1.w), y15 = hi16(d1.w);
        float part0 = x0 * c0.x + x1 * c0.y + x2 * c0.z + x3 * c0.w
                    + x4 * c1.x + x5 * c1.y + x6 * c1.z + x7 * c1.w
                    + x8 * c2.x + x9 * c2.y + x10 * c2.z + x11 * c2.w
                    + x12 * c3.x + x13 * c3.y + x14 * c3.z + x15 * c3.w;
        float part1 = y0 * c0.x + y1 * c0.y + y2 * c0.z + y3 * c0.w
                    + y4 * c1.x + y5 * c1.y + y6 * c1.z + y7 * c1.w
                    + y8 * c2.x + y9 * c2.y + y10 * c2.z + y11 * c2.w
                    + y12 * c3.x + y13 * c3.y + y14 * c3.z + y15 * c3.w;
        #pragma unroll
        for (int off = 1; off < 64; off <<= 1) {
            part0 += __shfl_xor(part0, off, 64);
            part1 += __shfl_xor(part1, off, 64);
        }
        const int n = n0 + j;
        const float rv0 = (n < nr && part0 > 0.f) ? 1.f / part0 : 0.f;
        const float rv1 = (n + 1 < nr && part1 > 0.f) ? 1.f / part1 : 0.f;
        acc[0]  += x0 * rv0 + y0 * rv1;   acc[1]  += x1 * rv0 + y1 * rv1;
        acc[2]  += x2 * rv0 + y2 * rv1;   acc[3]  += x3 * rv0 + y3 * rv1;
        acc[4]  += x4 * rv0 + y4 * rv1;   acc[5]  += x5 * rv0 + y5 * rv1;
        acc[6]  += x6 * rv0 + y6 * rv1;   acc[7]  += x7 * rv0 + y7 * rv1;
        acc[8]  += x8 * rv0 + y8 * rv1;   acc[9]  += x9 * rv0 + y9 * rv1;
        acc[10] += x10 * rv0 + y10 * rv1; acc[11] += x11 * rv0 + y11 * rv1;
        acc[12] += x12 * rv0 + y12 * rv1; acc[13] += x13 * rv0 + y13 * rv1;
        acc[14] += x14 * rv0 + y14 * rv1; acc[15] += x15 * rv0 + y15 * rv1;
        a0 = na0; d0 = nd0; a1 = na1; d1 = nd1;
    }
    red[w][2 * l]       = make_float4(acc[0], acc[1], acc[2], acc[3]);
    red[w][2 * l + 1]   = make_float4(acc[4], acc[5], acc[6], acc[7]);
    red[w][128 + 2 * l] = make_float4(acc[8], acc[9], acc[10], acc[11]);
    red[w][129 + 2 * l] = make_float4(acc[12], acc[13], acc[14], acc[15]);
    __syncthreads();
    const float4 r0 = red[0][t], r1 = red[1][t], r2 = red[2][t], r3 = red[3][t];
    float4 o = { r0.x + r1.x + r2.x + r3.x, r0.y + r1.y + r2.y + r3.y,
                 r0.z + r1.z + r2.z + r3.z, r0.w + r1.w + r2.w + r3.w };
    float* pp = pout + ((size_t)(b * SLOT) + blockIdx.y) * Mn;
    reinterpret_cast<float4*>(pp)[t] = o;
}

// ---- final pass: fold c, then f32 s re-read, in-wave row factor, output write.
// Depth-1 register prefetch of the next row's 4 f32x4 loads.
__global__ __launch_bounds__(256) void final_kernel(
        const float* __restrict__ s, const float* __restrict__ pin,
        const int* __restrict__ nrows, const int* __restrict__ ncols,
        float* __restrict__ out) {
    __shared__ float cs[1024];       // 4 KB
    const int b = blockIdx.x;
    const int t = threadIdx.x, w = t >> 6, l = t & 63;
    fold_c(pin, ncols, b, t, cs);
    __syncthreads();
    f32x4 cc[4];
    #pragma unroll
    for (int k = 0; k < 4; ++k)
        cc[k] = *reinterpret_cast<const f32x4*>(&cs[256 * k + 4 * l]);
    const int n0 = blockIdx.y * 32 + w * 8;
    const int nr = nrows[b];
    const size_t roff0 = ((size_t)b * Nn + n0) * Mn;
    const f32x4* row0 = reinterpret_cast<const f32x4*>(s + roff0);
    f32x4 a[4];
    #pragma unroll
    for (int k = 0; k < 4; ++k)
        a[k] = __builtin_nontemporal_load(row0 + 64 * k + l);
    for (int j = 0; j < 8; ++j) {
        f32x4 na[4] = {};
        if (j < 7) {
            const f32x4* nrow = row0 + (size_t)(j + 1) * (Mn / 4);
            #pragma unroll
            for (int k = 0; k < 4; ++k)
                na[k] = __builtin_nontemporal_load(nrow + 64 * k + l);
        }
        float part = 0.f;
        #pragma unroll
        for (int k = 0; k < 4; ++k) {
            a[k] += EPS;
            part += a[k].x * cc[k].x + a[k].y * cc[k].y
                  + a[k].z * cc[k].z + a[k].w * cc[k].w;
        }
        #pragma unroll
        for (int off = 1; off < 64; off <<= 1) part += __shfl_xor(part, off, 64);
        const int n = n0 + j;
        const float rv = (n < nr && part > 0.f) ? 1.f / part : 0.f;
        f32x4* orow = reinterpret_cast<f32x4*>(out + roff0 + (size_t)j * Mn);
        #pragma unroll
        for (int k = 0; k < 4; ++k) {
            f32x4 o;
            o.x = a[k].x * cc[k].x * rv;
            o.y = a[k].y * cc[k].y * rv;
            o.z = a[k].z * cc[k].z * rv;
            o.w = a[k].w * cc[k].w * rv;
            __builtin_nontemporal_store(o, orow + 64 * k + l);
        }
        #pragma unroll
        for (int k = 0; k < 4; ++k) a[k] = na[k];
    }
}

extern "C" void kernel_launch(void* const* d_in, const int* in_sizes, int n_in,
                              void* d_out, int out_size, void* d_ws, size_t ws_size,
                              hipStream_t stream) {
    const float* s     = (const float*)d_in[0];
    const int*   nrows = (const int*)d_in[1];
    const int*   ncols = (const int*)d_in[2];
    float* out = (float*)d_out;

    // workspace: sc fp16 [B*N*M] (128 MiB) | pA [B*16*M] (4 MB) | pB (4 MB)
    unsigned short* sc = (unsigned short*)d_ws;
    float* pA = (float*)(sc + (size_t)Bn * Nn * Mn);
    float* pB = pA + (size_t)Bn * SLOT * Mn;

    // i=0: col-sum pass fused with fp16 compression (unmasked, r==1)
    fuse0_kernel<<<dim3(Bn, NSPLIT), 256, 0, stream>>>(s, sc, pA);
    // i=1..8: four fused (c-finalize + row-norm + col-sum) sweeps, ping-pong p
    rowcol_kernel<<<dim3(Bn, NSPLIT), 256, 0, stream>>>(sc, pA, nrows, ncols, pB);
    rowcol_kernel<<<dim3(Bn, NSPLIT), 256, 0, stream>>>(sc, pB, nrows, ncols, pA);
    rowcol_kernel<<<dim3(Bn, NSPLIT), 256, 0, stream>>>(sc, pA, nrows, ncols, pB);
    rowcol_kernel<<<dim3(Bn, NSPLIT), 256, 0, stream>>>(sc, pB, nrows, ncols, pA);
    // i=9: c-finalize + final row normalization fused with output write (f32)
    final_kernel<<<dim3(Bn, Nn / 32), 256, 0, stream>>>(s, pA, nrows, ncols, out);
}